// Round 28
// baseline (105.991 us; speedup 1.0000x reference)
//
#include <hip/hip_runtime.h>
#include <hip/hip_bf16.h>

#define BATCH 16
#define SEQ   2048
#define HD    128
#define TB    64            // proj tile rows
#define QB3   64            // attn q-tile rows
#define NT3   (SEQ/QB3)     // 32 q-tiles per batch
#define PLANE ((size_t)BATCH*SEQ*HD)   // shorts per ws plane
#define WBOFF (3*PLANE)                // bf16 weights offset (shorts)
#define MLOFF (3*PLANE + 49152)        // m/l region offset (shorts)

typedef __attribute__((ext_vector_type(8))) short bf16x8;
typedef __attribute__((ext_vector_type(4))) float f32x4;
typedef __attribute__((ext_vector_type(2))) unsigned int u32x2;

#define MFMA(a,b,c) __builtin_amdgcn_mfma_f32_16x16x32_bf16(a,b,c,0,0,0)

__device__ __forceinline__ short f2bf(float f){
  union{float f; unsigned u;} v; v.f = f;
  unsigned r = (v.u + 0x7FFFu + ((v.u>>16)&1u))>>16;
  return (short)r;
}
__device__ __forceinline__ float bf2f(short s){
  union{unsigned u; float f;} v; v.u = ((unsigned)(unsigned short)s)<<16; return v.f;
}
__device__ __forceinline__ unsigned packbf(float lo, float hi){
  return ((unsigned)(unsigned short)f2bf(hi) << 16) | (unsigned short)f2bf(lo);
}
__device__ __forceinline__ bf16x8 pack8(f32x4 a, f32x4 b){
  bf16x8 r;
  r[0]=f2bf(a[0]); r[1]=f2bf(a[1]); r[2]=f2bf(a[2]); r[3]=f2bf(a[3]);
  r[4]=f2bf(b[0]); r[5]=f2bf(b[1]); r[6]=f2bf(b[2]); r[7]=f2bf(b[3]);
  return r;
}
__device__ __forceinline__ bf16x8 ldfrag(const float* base, size_t eo){
  const float* p = base + eo;
  return pack8(*(const f32x4*)p, *(const f32x4*)(p+4));
}

// ---------------- kernel 0: W fp32 -> bf16 once ------------------------------
__global__ __launch_bounds__(256)
void wconv_kernel(const float* __restrict__ Wq, const float* __restrict__ Wk,
                  const float* __restrict__ Wv, short* __restrict__ wb)
{
  int i = (blockIdx.x*256 + threadIdx.x)*8;
  const float* src = (i < 16384) ? Wq : (i < 32768 ? Wk : Wv);
  int off = i & 16383;
  f32x4 a = *(const f32x4*)(src + off);
  f32x4 b = *(const f32x4*)(src + off + 4);
  *(bf16x8*)(wb + i) = pack8(a, b);
}

// ---------------- kernel 1: K/V projections -> ws images (bf16) --------------
__global__ __launch_bounds__(256)
void proj_kernel(const float* __restrict__ k, const float* __restrict__ v,
                 const float* __restrict__ bk, const float* __restrict__ bv,
                 const short* __restrict__ wb, short* __restrict__ ws)
{
  __shared__ __align__(16) short T[TB*136];    // [s_local][h] bounce (z==1)
  __shared__ __align__(16) short VT[HD*72];    // [h][s_local] bounce (z==2)

  const int z = blockIdx.y + 1;                // 1=K, 2=V
  const float* x  = (z==1) ? k  : v;
  const float* bb = (z==1) ? bk : bv;
  const short* W  = wb + (size_t)z*HD*HD;

  const int tid = threadIdx.x;
  const int w = tid>>6, l = tid&63, li = l&15, g = l>>4;
  const int bx = blockIdx.x;                   // 64-row tile id (b = bx>>5)
  const int rowbase = bx*TB + w*16;

  bf16x8 afr[4];
  const float* xr = x + (size_t)(rowbase+li)*HD + g*8;
  #pragma unroll
  for (int ks=0; ks<4; ks++) afr[ks] = ldfrag(xr, (size_t)ks*32);

  f32x4 acc[8];
  #pragma unroll
  for (int ct=0; ct<8; ct++) acc[ct] = (f32x4){0.f,0.f,0.f,0.f};
  #pragma unroll
  for (int ct=0; ct<8; ct++){
    #pragma unroll
    for (int ks=0; ks<4; ks++){
      bf16x8 bfr = *(const bf16x8*)(W + (size_t)(ct*16+li)*HD + ks*32 + g*8);
      acc[ct] = MFMA(afr[ks], bfr, acc[ct]);
    }
  }

  const int img  = (bx>>1);                    // 128-row image id
  const int half = bx & 1;                     // which 64-row half

  if (z == 1){
    #pragma unroll
    for (int ct=0; ct<8; ct++){
      float bias = bb[ct*16+li];
      #pragma unroll
      for (int r=0; r<4; r++)
        T[(w*16+g*4+r)*136 + ct*16+li] = f2bf(acc[ct][r] + bias);
    }
    __syncthreads();
    short* dst = ws + PLANE + (size_t)img*16384;
    #pragma unroll
    for (int it=0; it<4; it++){
      int c = tid + it*256, row = c>>4, c8 = c&15;
      int r128 = half*64 + row;
      int chunk = r128*16 + (c8 ^ (r128&7));
      *(bf16x8*)(dst + chunk*8) = *(const bf16x8*)&T[row*136 + c8*8];
    }
  } else {
    #pragma unroll
    for (int ct=0; ct<8; ct++){
      float bias = bb[ct*16+li];
      #pragma unroll
      for (int r=0; r<4; r++)
        VT[(ct*16+li)*72 + w*16+g*4+r] = f2bf(acc[ct][r] + bias);
    }
    __syncthreads();
    short* dst = ws + 2*PLANE + (size_t)img*16384;
    const int d = tid>>1, hf = tid&1;
    #pragma unroll
    for (int j=0; j<4; j++){
      int c8l = hf*4 + j;
      int c8g = half*8 + c8l;
      int chunk = d*16 + (c8g ^ (d&7));
      *(bf16x8*)(dst + chunk*8) = *(const bf16x8*)&VT[d*72 + c8l*8];
    }
  }
}

// ---------------- kernel 2: fused Q-proj + causal flash attention (split-K) --
// Grid 768: bid<512 = split halves of qt>=16 tiles (8..16 iters, partials to
// Q-plane); bid>=512 = direct qt<16 tiles (1..16 iters, straight to out).
// Long blocks dispatch first (LPT); 256 backfill blocks kill the tail.
__global__ __launch_bounds__(256, 2)
void attn_kernel(const float* __restrict__ qin, const float* __restrict__ bq,
                 short* __restrict__ ws, float* __restrict__ out)
{
  __shared__ __align__(16) short KVL[2][16384]; // [buf][K 8192 | V 8192] shorts
  __shared__ __align__(16) short PL[4][16*72];  // per-wave P, padded

  const short* wb = ws + WBOFF;
  const int bid = blockIdx.x;

  int b, qt, kt0, kt1, pidx;
  bool direct;
  if (bid < 512){                               // split blocks (long, first)
    const int xcd = bid & 7, r = bid >> 3;      // r 0..63
    b = xcd*2 + (r >> 5);
    const int t = r & 31;
    qt = 31 - (t >> 1);                         // 31..16, descending length
    const int h = t & 1;
    const int sp = (qt + 1) >> 1;               // split point (8..16)
    kt0 = h ? sp : 0;
    kt1 = h ? qt : sp - 1;
    pidx = (b*16 + (qt - 16))*2 + h;            // 0..511
    direct = false;
  } else {                                      // direct blocks (short, last)
    const int db = bid - 512;                   // 0..255
    const int xcd = db & 7, r2 = db >> 3;       // r2 0..31
    b = xcd*2 + (r2 >> 4);
    qt = 15 - (r2 & 15);                        // 15..0, descending length
    kt0 = 0; kt1 = qt; pidx = 0;
    direct = true;
  }

  const int tid = threadIdx.x;
  const int w = tid>>6, l = tid&63, li = l&15, g = l>>4;

  const short* KimgB = ws + PLANE   + (size_t)b*(SEQ/128)*16384;
  const short* VimgB = ws + 2*PLANE + (size_t)b*(SEQ/128)*16384;

  const size_t qbase = (size_t)b*SEQ + qt*QB3;
  short* Pw = &PL[w][0];
  const float sc = 0.088388347648318447f;       // 1/sqrt(128)

  bf16x8 stg[8];
  #define LOADT(kt_) do{                                                     \
    const short* sK = KimgB + (size_t)((kt_)>>1)*16384 + ((kt_)&1)*8192;     \
    const short* sV = VimgB + (size_t)((kt_)>>1)*16384;                      \
    const int vh = ((kt_)&1)*8;                                              \
    _Pragma("unroll")                                                        \
    for (int j=0;j<4;j++) stg[j] = *(const bf16x8*)(sK + (tid + j*256)*8);   \
    _Pragma("unroll")                                                        \
    for (int j=0;j<4;j++){                                                   \
      int i = tid + j*256, d = i>>3, c8s = i&7;                              \
      stg[4+j] = *(const bf16x8*)(sV + (d*16 + vh + c8s)*8);                 \
    }                                                                        \
  }while(0)
  #define WRT(nb_) do{                                                      \
    short* dK = &KVL[nb_][0];                                               \
    short* dV = &KVL[nb_][8192];                                            \
    _Pragma("unroll")                                                       \
    for (int j=0;j<4;j++) *(bf16x8*)(dK + (tid+j*256)*8) = stg[j];          \
    _Pragma("unroll")                                                       \
    for (int j=0;j<4;j++) *(bf16x8*)(dV + (tid+j*256)*8) = stg[4+j];        \
  }while(0)

  LOADT(kt0);                                   // overlap with Q-proj below

  // ---- prologue: Qh = q @ Wq^T + bq, transpose via KVL[0] bounce ----
  bf16x8 qfr[4];
  {
    bf16x8 xa[4];
    const float* xr = qin + (qbase + w*16 + li)*HD + g*8;
    #pragma unroll
    for (int ks=0; ks<4; ks++) xa[ks] = ldfrag(xr, (size_t)ks*32);
    f32x4 qa[8];
    #pragma unroll
    for (int ct=0; ct<8; ct++) qa[ct] = (f32x4){0.f,0.f,0.f,0.f};
    #pragma unroll
    for (int ct=0; ct<8; ct++){
      #pragma unroll
      for (int ks=0; ks<4; ks++){
        bf16x8 wf = *(const bf16x8*)(wb + (size_t)(ct*16+li)*HD + ks*32 + g*8);
        qa[ct] = MFMA(xa[ks], wf, qa[ct]);
      }
    }
    short* T = &KVL[0][0];                      // bounce (64 x 136 shorts)
    #pragma unroll
    for (int ct=0; ct<8; ct++){
      float bias = bq[ct*16+li];
      #pragma unroll
      for (int r=0; r<4; r++)
        T[(w*16+g*4+r)*136 + ct*16+li] = f2bf(qa[ct][r] + bias);
    }
    __syncthreads();
    #pragma unroll
    for (int ks=0; ks<4; ks++)
      qfr[ks] = *(const bf16x8*)&T[(w*16+li)*136 + ks*32 + g*8];
    __syncthreads();                            // all reads done before WRT(0)
  }

  f32x4 oacc[8];
  #pragma unroll
  for (int dt=0; dt<8; dt++) oacc[dt] = (f32x4){0.f,0.f,0.f,0.f};
  float mreg = -1e30f, lreg = 0.f;              // for q-row (w*16 + li)

  WRT(0); __syncthreads();
  int cur = 0;

  for (int kt=kt0; kt<=kt1; kt++){
    const bool pre = (kt < kt1);
    if (pre) LOADT(kt+1);

    const short* KL = &KVL[cur][0];
    const short* VL = &KVL[cur][8192];

    // ---- swapped QK^T : lane holds S[q=li][k = ct*16 + g*4 + r], ct<4
    f32x4 st[4];
    #pragma unroll
    for (int ct=0; ct<4; ct++) st[ct] = (f32x4){0.f,0.f,0.f,0.f};
    __builtin_amdgcn_s_setprio(1);
    #pragma unroll
    for (int ct=0; ct<4; ct++){
      const int row = ct*16 + li;               // K row (A-frag)
      #pragma unroll
      for (int ks=0; ks<4; ks++){
        const int chunk = row*16 + ((ks*4 + g) ^ (row&7));
        bf16x8 kfr = *(const bf16x8*)&KL[chunk*8];
        st[ct] = MFMA(kfr, qfr[ks], st[ct]);    // SWAPPED operands
      }
    }
    __builtin_amdgcn_s_setprio(0);

    // ---- lane-local online softmax with defer-max (T13, THR=8)
    float sv[4][4];
    float pm = -1e30f;
    const bool diag = (kt == qt);
    const int qloc = w*16 + li;
    #pragma unroll
    for (int ct=0; ct<4; ct++){
      #pragma unroll
      for (int r=0; r<4; r++){
        float x = st[ct][r]*sc;
        if (diag && (ct*16 + g*4 + r) > qloc) x = -1e30f;
        sv[ct][r] = x;
        pm = fmaxf(pm, x);
      }
    }
    pm = fmaxf(pm, __shfl_xor(pm, 16));
    pm = fmaxf(pm, __shfl_xor(pm, 32));
    const bool resc = !__all(pm - mreg <= 8.f);
    float sclq = 1.f;
    if (resc){
      float mn = fmaxf(mreg, pm);
      sclq = __expf(mreg - mn);
      mreg = mn;
      lreg *= sclq;
    }
    float psum = 0.f;
    #pragma unroll
    for (int ct=0; ct<4; ct++){
      #pragma unroll
      for (int r=0; r<4; r++){
        float p = __expf(sv[ct][r] - mreg);     // bounded by e^8
        sv[ct][r] = p;
        psum += p;
      }
    }
    psum += __shfl_xor(psum, 16);
    psum += __shfl_xor(psum, 32);
    lreg += psum;

    // ---- P -> LDS first (DS latency hides under rescale VALU below)
    #pragma unroll
    for (int c4=0; c4<4; c4++){
      u32x2 pw;
      pw[0] = packbf(sv[c4][0], sv[c4][1]);
      pw[1] = packbf(sv[c4][2], sv[c4][3]);
      *(u32x2*)&Pw[li*72 + c4*16 + g*4] = pw;   // row q=li, k=c4*16+g*4..+3
    }

    // ---- conditional O rescale (usually skipped by defer-max)
    if (resc){
      float sclo[4];
      #pragma unroll
      for (int r=0; r<4; r++) sclo[r] = __shfl(sclq, g*4 + r);
      #pragma unroll
      for (int dt=0; dt<8; dt++){
        #pragma unroll
        for (int r=0; r<4; r++) oacc[dt][r] *= sclo[r];
      }
    }

    // ---- PV over k 0..63
    __builtin_amdgcn_s_setprio(1);
    #pragma unroll
    for (int ks2=0; ks2<2; ks2++){
      bf16x8 afr = *(const bf16x8*)&Pw[li*72 + ks2*32 + g*8];
      #pragma unroll
      for (int dt=0; dt<8; dt++){
        const int d = dt*16 + li;
        const int chunk = d*8 + ((ks2*4 + g) ^ (d&7));
        bf16x8 bfr = *(const bf16x8*)&VL[chunk*8];
        oacc[dt] = MFMA(afr, bfr, oacc[dt]);
      }
    }
    __builtin_amdgcn_s_setprio(0);

    if (pre) WRT(cur^1);
    __syncthreads();                            // single barrier per iteration
    cur ^= 1;
  } // kt

  if (direct){
    // ---- epilogue: normalize + fp32 out
    float lso[4];
    #pragma unroll
    for (int r=0; r<4; r++) lso[r] = __shfl(lreg, g*4 + r);
    float* Ob = out + qbase*HD;
    #pragma unroll
    for (int dt=0; dt<8; dt++){
      #pragma unroll
      for (int r=0; r<4; r++){
        Ob[(size_t)(w*16 + g*4 + r)*HD + dt*16 + li] = oacc[dt][r] / lso[r];
      }
    }
  } else {
    // ---- epilogue: unnormalized bf16 partial -> Q-plane + (m,l) -> ml region
    short* Pp = ws + (size_t)pidx*8192;         // 64x128 bf16
    #pragma unroll
    for (int dt=0; dt<8; dt++){
      #pragma unroll
      for (int r=0; r<4; r++){
        Pp[(w*16 + g*4 + r)*HD + dt*16 + li] = f2bf(oacc[dt][r]);
      }
    }
    if (l < 16){                                // canonical lanes (g==0)
      float* ml = (float*)(ws + MLOFF);
      ml[pidx*128 + (w*16 + li)*2    ] = mreg;
      ml[pidx*128 + (w*16 + li)*2 + 1] = lreg;
    }
  }
  #undef LOADT
  #undef WRT
}

// ---------------- kernel 3: merge split-K partials ---------------------------
__global__ __launch_bounds__(256)
void merge_kernel(const short* __restrict__ ws, float* __restrict__ out)
{
  const int mb = blockIdx.x;                    // 256 blocks
  const int xcd = mb & 7, r3 = mb >> 3;         // r3 0..31
  const int b  = xcd*2 + (r3 >> 4);
  const int qt = 16 + (r3 & 15);

  const int tid = threadIdx.x;
  const int row = tid >> 2;                     // 0..63
  const int cg  = (tid & 3)*32;                 // column group base

  const int p0 = (b*16 + (qt - 16))*2;
  const short* P0 = ws + (size_t)p0*8192;
  const short* P1 = ws + (size_t)(p0+1)*8192;
  const float* ml = (const float*)(ws + MLOFF);

  const float m0 = ml[p0*128 + row*2],     l0 = ml[p0*128 + row*2 + 1];
  const float m1 = ml[(p0+1)*128 + row*2], l1 = ml[(p0+1)*128 + row*2 + 1];
  const float M  = fmaxf(m0, m1);
  const float w0 = __expf(m0 - M), w1 = __expf(m1 - M);
  const float inv = 1.f / (l0*w0 + l1*w1);

  float* Ob = out + ((size_t)b*SEQ + qt*QB3 + row)*HD + cg;
  const short* a0 = P0 + row*HD + cg;
  const short* a1 = P1 + row*HD + cg;
  #pragma unroll
  for (int j8=0; j8<4; j8++){
    bf16x8 x0 = *(const bf16x8*)(a0 + j8*8);
    bf16x8 x1 = *(const bf16x8*)(a1 + j8*8);
    #pragma unroll
    for (int e=0; e<8; e++){
      Ob[j8*8 + e] = (bf2f(x0[e])*w0 + bf2f(x1[e])*w1) * inv;
    }
  }
}

// ---------------- launch -----------------------------------------------------
// d_in = [q, k, v, Wq, bq, Wk, bk, Wv, bv, mask] (confirmed R15).
// ws: partials(Q-plane) | Kimg | Vimg | Wbf16 | ml (25.5 MB).
extern "C" void kernel_launch(void* const* d_in, const int* in_sizes, int n_in,
                              void* d_out, int out_size, void* d_ws, size_t ws_size,
                              hipStream_t stream)
{
  short* ws = (short*)d_ws;
  short* wb = ws + WBOFF;

  wconv_kernel<<<24, 256, 0, stream>>>(
      (const float*)d_in[3], (const float*)d_in[5], (const float*)d_in[7], wb);

  dim3 pg(BATCH*SEQ/TB, 2);                      // K and V planes only
  proj_kernel<<<pg, 256, 0, stream>>>(
      (const float*)d_in[1], (const float*)d_in[2],
      (const float*)d_in[6], (const float*)d_in[8],
      wb, ws);

  attn_kernel<<<dim3(768), 256, 0, stream>>>(
      (const float*)d_in[0], (const float*)d_in[4], ws, (float*)d_out);

  merge_kernel<<<dim3(256), 256, 0, stream>>>(ws, (float*)d_out);
}

// Round 29
// 92.516 us; speedup vs baseline: 1.1457x; 1.1457x over previous
//
#include <hip/hip_runtime.h>
#include <hip/hip_bf16.h>

#define BATCH 16
#define SEQ   2048
#define HD    128
#define TB    64            // proj tile rows
#define QB3   64            // attn q-tile rows
#define NT3   (SEQ/QB3)     // 32 q-tiles per batch
#define PLANE ((size_t)BATCH*SEQ*HD)   // shorts per ws plane

typedef __attribute__((ext_vector_type(8))) short bf16x8;
typedef __attribute__((ext_vector_type(4))) float f32x4;
typedef __attribute__((ext_vector_type(2))) unsigned int u32x2;

#define MFMA(a,b,c) __builtin_amdgcn_mfma_f32_16x16x32_bf16(a,b,c,0,0,0)

__device__ __forceinline__ short f2bf(float f){
  union{float f; unsigned u;} v; v.f = f;
  unsigned r = (v.u + 0x7FFFu + ((v.u>>16)&1u))>>16;
  return (short)r;
}
__device__ __forceinline__ unsigned packbf(float lo, float hi){
  return ((unsigned)(unsigned short)f2bf(hi) << 16) | (unsigned short)f2bf(lo);
}
__device__ __forceinline__ bf16x8 pack8(f32x4 a, f32x4 b){
  bf16x8 r;
  r[0]=f2bf(a[0]); r[1]=f2bf(a[1]); r[2]=f2bf(a[2]); r[3]=f2bf(a[3]);
  r[4]=f2bf(b[0]); r[5]=f2bf(b[1]); r[6]=f2bf(b[2]); r[7]=f2bf(b[3]);
  return r;
}
__device__ __forceinline__ bf16x8 ldfrag(const float* base, size_t eo){
  const float* p = base + eo;
  return pack8(*(const f32x4*)p, *(const f32x4*)(p+4));
}

// ---------------- kernel 0: W fp32 -> bf16 once ------------------------------
__global__ __launch_bounds__(256)
void wconv_kernel(const float* __restrict__ Wq, const float* __restrict__ Wk,
                  const float* __restrict__ Wv, short* __restrict__ wb)
{
  int i = (blockIdx.x*256 + threadIdx.x)*8;
  const float* src = (i < 16384) ? Wq : (i < 32768 ? Wk : Wv);
  int off = i & 16383;
  f32x4 a = *(const f32x4*)(src + off);
  f32x4 b = *(const f32x4*)(src + off + 4);
  *(bf16x8*)(wb + i) = pack8(a, b);
}

// ---------------- kernel 1: K/V projections -> ws images (bf16) --------------
// z=1: Kh 32KB images [128 rows]: chunk(r,c8)=r*16+(c8^(r&7)).
// z=2: Vh^T 32KB images [d][c8 0..15]: chunk(d,c8)=d*16+(c8^(d&7)).
__global__ __launch_bounds__(256)
void proj_kernel(const float* __restrict__ k, const float* __restrict__ v,
                 const float* __restrict__ bk, const float* __restrict__ bv,
                 const short* __restrict__ wb, short* __restrict__ ws)
{
  __shared__ __align__(16) short T[TB*136];    // [s_local][h] bounce (z==1)
  __shared__ __align__(16) short VT[HD*72];    // [h][s_local] bounce (z==2)

  const int z = blockIdx.y + 1;                // 1=K, 2=V
  const float* x  = (z==1) ? k  : v;
  const float* bb = (z==1) ? bk : bv;
  const short* W  = wb + (size_t)z*HD*HD;

  const int tid = threadIdx.x;
  const int w = tid>>6, l = tid&63, li = l&15, g = l>>4;
  const int bx = blockIdx.x;                   // 64-row tile id (b = bx>>5)
  const int rowbase = bx*TB + w*16;

  bf16x8 afr[4];
  const float* xr = x + (size_t)(rowbase+li)*HD + g*8;
  #pragma unroll
  for (int ks=0; ks<4; ks++) afr[ks] = ldfrag(xr, (size_t)ks*32);

  f32x4 acc[8];
  #pragma unroll
  for (int ct=0; ct<8; ct++) acc[ct] = (f32x4){0.f,0.f,0.f,0.f};
  #pragma unroll
  for (int ct=0; ct<8; ct++){
    #pragma unroll
    for (int ks=0; ks<4; ks++){
      bf16x8 bfr = *(const bf16x8*)(W + (size_t)(ct*16+li)*HD + ks*32 + g*8);
      acc[ct] = MFMA(afr[ks], bfr, acc[ct]);
    }
  }

  const int img  = (bx>>1);                    // 128-row image id
  const int half = bx & 1;                     // which 64-row half

  if (z == 1){
    #pragma unroll
    for (int ct=0; ct<8; ct++){
      float bias = bb[ct*16+li];
      #pragma unroll
      for (int r=0; r<4; r++)
        T[(w*16+g*4+r)*136 + ct*16+li] = f2bf(acc[ct][r] + bias);
    }
    __syncthreads();
    short* dst = ws + PLANE + (size_t)img*16384;
    #pragma unroll
    for (int it=0; it<4; it++){
      int c = tid + it*256, row = c>>4, c8 = c&15;
      int r128 = half*64 + row;
      int chunk = r128*16 + (c8 ^ (r128&7));
      *(bf16x8*)(dst + chunk*8) = *(const bf16x8*)&T[row*136 + c8*8];
    }
  } else {
    #pragma unroll
    for (int ct=0; ct<8; ct++){
      float bias = bb[ct*16+li];
      #pragma unroll
      for (int r=0; r<4; r++)
        VT[(ct*16+li)*72 + w*16+g*4+r] = f2bf(acc[ct][r] + bias);
    }
    __syncthreads();
    short* dst = ws + 2*PLANE + (size_t)img*16384;
    const int d = tid>>1, hf = tid&1;
    #pragma unroll
    for (int j=0; j<4; j++){
      int c8l = hf*4 + j;
      int c8g = half*8 + c8l;
      int chunk = d*16 + (c8g ^ (d&7));
      *(bf16x8*)(dst + chunk*8) = *(const bf16x8*)&VT[d*72 + c8l*8];
    }
  }
}

// ---------------- kernel 2: fused Q-proj + causal flash attention ------------
// R27 loop (reg-staged dbuf, 1 barrier/iter, 2 blocks/CU, defer-max, P-reorder)
// + prologue barrier elimination: bounce is WAVE-PRIVATE (wave w writes and
// reads only rows w*16..w*16+15), placed in KVL[1] (disjoint from WRT(0)'s
// KVL[0]) -> zero prologue barriers; single pre-loop barrier suffices.
__global__ __launch_bounds__(256, 2)
void attn_kernel(const float* __restrict__ qin, const float* __restrict__ bq,
                 const short* __restrict__ wb, const short* __restrict__ ws,
                 float* __restrict__ out)
{
  __shared__ __align__(16) short KVL[2][16384]; // [buf][K 8192 | V 8192] shorts
  __shared__ __align__(16) short PL[4][16*72];  // per-wave P, padded

  const int bid  = blockIdx.x;                  // 512 blocks
  const int xcd  = bid & 7, slot = bid >> 3;    // slot 0..63
  const int b    = xcd*2 + (slot >> 5);
  const int sl   = slot & 31;
  const int qt   = (slot < 32) ? sl : (31 - sl);  // co-resident pair ~33 iters

  const int tid = threadIdx.x;
  const int w = tid>>6, l = tid&63, li = l&15, g = l>>4;

  const short* KimgB = ws + PLANE   + (size_t)b*(SEQ/128)*16384;
  const short* VimgB = ws + 2*PLANE + (size_t)b*(SEQ/128)*16384;

  const size_t qbase = (size_t)b*SEQ + qt*QB3;
  short* Pw = &PL[w][0];
  const float sc = 0.088388347648318447f;       // 1/sqrt(128)

  // staging regs + macros (reg-staged: loads get a full iteration to land)
  bf16x8 stg[8];
  #define LOADT(kt_) do{                                                     \
    const short* sK = KimgB + (size_t)((kt_)>>1)*16384 + ((kt_)&1)*8192;     \
    const short* sV = VimgB + (size_t)((kt_)>>1)*16384;                      \
    const int vh = ((kt_)&1)*8;                                              \
    _Pragma("unroll")                                                        \
    for (int j=0;j<4;j++) stg[j] = *(const bf16x8*)(sK + (tid + j*256)*8);   \
    _Pragma("unroll")                                                        \
    for (int j=0;j<4;j++){                                                   \
      int i = tid + j*256, d = i>>3, c8s = i&7;                              \
      stg[4+j] = *(const bf16x8*)(sV + (d*16 + vh + c8s)*8);                 \
    }                                                                        \
  }while(0)
  #define WRT(nb_) do{                                                      \
    short* dK = &KVL[nb_][0];                                               \
    short* dV = &KVL[nb_][8192];                                            \
    _Pragma("unroll")                                                       \
    for (int j=0;j<4;j++) *(bf16x8*)(dK + (tid+j*256)*8) = stg[j];          \
    _Pragma("unroll")                                                       \
    for (int j=0;j<4;j++) *(bf16x8*)(dV + (tid+j*256)*8) = stg[4+j];        \
  }while(0)

  LOADT(0);                                     // overlap with Q-proj below

  // ---- prologue: Qh = q @ Wq^T + bq; wave-private bounce in KVL[1] ----
  bf16x8 qfr[4];
  {
    bf16x8 xa[4];
    const float* xr = qin + (qbase + w*16 + li)*HD + g*8;
    #pragma unroll
    for (int ks=0; ks<4; ks++) xa[ks] = ldfrag(xr, (size_t)ks*32);
    f32x4 qa[8];
    #pragma unroll
    for (int ct=0; ct<8; ct++) qa[ct] = (f32x4){0.f,0.f,0.f,0.f};
    #pragma unroll
    for (int ct=0; ct<8; ct++){
      #pragma unroll
      for (int ks=0; ks<4; ks++){
        bf16x8 wf = *(const bf16x8*)(wb + (size_t)(ct*16+li)*HD + ks*32 + g*8);
        qa[ct] = MFMA(xa[ks], wf, qa[ct]);
      }
    }
    short* T = &KVL[1][0];                      // wave-private rows (64 x 136)
    #pragma unroll
    for (int ct=0; ct<8; ct++){
      float bias = bq[ct*16+li];
      #pragma unroll
      for (int r=0; r<4; r++)
        T[(w*16+g*4+r)*136 + ct*16+li] = f2bf(qa[ct][r] + bias);
    }
    // no barrier: wave w reads exactly the rows it wrote (lgkmcnt suffices)
    #pragma unroll
    for (int ks=0; ks<4; ks++)
      qfr[ks] = *(const bf16x8*)&T[(w*16+li)*136 + ks*32 + g*8];
  }

  f32x4 oacc[8];
  #pragma unroll
  for (int dt=0; dt<8; dt++) oacc[dt] = (f32x4){0.f,0.f,0.f,0.f};
  float mreg = -1e30f, lreg = 0.f;              // for q-row (w*16 + li)

  WRT(0);                                       // targets KVL[0], disjoint
  __syncthreads();                              // single pre-loop barrier
  int cur = 0;

  for (int kt=0; kt<=qt; kt++){
    const bool pre = (kt < qt);
    if (pre) LOADT(kt+1);

    const short* KL = &KVL[cur][0];
    const short* VL = &KVL[cur][8192];

    // ---- swapped QK^T : lane holds S[q=li][k = ct*16 + g*4 + r], ct<4
    f32x4 st[4];
    #pragma unroll
    for (int ct=0; ct<4; ct++) st[ct] = (f32x4){0.f,0.f,0.f,0.f};
    __builtin_amdgcn_s_setprio(1);
    #pragma unroll
    for (int ct=0; ct<4; ct++){
      const int row = ct*16 + li;               // K row (A-frag)
      #pragma unroll
      for (int ks=0; ks<4; ks++){
        const int chunk = row*16 + ((ks*4 + g) ^ (row&7));
        bf16x8 kfr = *(const bf16x8*)&KL[chunk*8];
        st[ct] = MFMA(kfr, qfr[ks], st[ct]);    // SWAPPED operands
      }
    }
    __builtin_amdgcn_s_setprio(0);

    // ---- lane-local online softmax with defer-max (T13, THR=8)
    float sv[4][4];
    float pm = -1e30f;
    const bool diag = (kt == qt);
    const int qloc = w*16 + li;
    #pragma unroll
    for (int ct=0; ct<4; ct++){
      #pragma unroll
      for (int r=0; r<4; r++){
        float x = st[ct][r]*sc;
        if (diag && (ct*16 + g*4 + r) > qloc) x = -1e30f;
        sv[ct][r] = x;
        pm = fmaxf(pm, x);
      }
    }
    pm = fmaxf(pm, __shfl_xor(pm, 16));
    pm = fmaxf(pm, __shfl_xor(pm, 32));
    const bool resc = !__all(pm - mreg <= 8.f);
    float sclq = 1.f;
    if (resc){
      float mn = fmaxf(mreg, pm);
      sclq = __expf(mreg - mn);
      mreg = mn;
      lreg *= sclq;
    }
    float psum = 0.f;
    #pragma unroll
    for (int ct=0; ct<4; ct++){
      #pragma unroll
      for (int r=0; r<4; r++){
        float p = __expf(sv[ct][r] - mreg);     // bounded by e^8
        sv[ct][r] = p;
        psum += p;
      }
    }
    psum += __shfl_xor(psum, 16);
    psum += __shfl_xor(psum, 32);
    lreg += psum;

    // ---- P -> LDS first (DS latency hides under rescale VALU below)
    #pragma unroll
    for (int c4=0; c4<4; c4++){
      u32x2 pw;
      pw[0] = packbf(sv[c4][0], sv[c4][1]);
      pw[1] = packbf(sv[c4][2], sv[c4][3]);
      *(u32x2*)&Pw[li*72 + c4*16 + g*4] = pw;   // row q=li, k=c4*16+g*4..+3
    }

    // ---- conditional O rescale (usually skipped by defer-max)
    if (resc){
      float sclo[4];
      #pragma unroll
      for (int r=0; r<4; r++) sclo[r] = __shfl(sclq, g*4 + r);
      #pragma unroll
      for (int dt=0; dt<8; dt++){
        #pragma unroll
        for (int r=0; r<4; r++) oacc[dt][r] *= sclo[r];
      }
    }

    // ---- PV over k 0..63
    __builtin_amdgcn_s_setprio(1);
    #pragma unroll
    for (int ks2=0; ks2<2; ks2++){
      bf16x8 afr = *(const bf16x8*)&Pw[li*72 + ks2*32 + g*8];
      #pragma unroll
      for (int dt=0; dt<8; dt++){
        const int d = dt*16 + li;
        const int chunk = d*8 + ((ks2*4 + g) ^ (d&7));
        bf16x8 bfr = *(const bf16x8*)&VL[chunk*8];
        oacc[dt] = MFMA(afr, bfr, oacc[dt]);
      }
    }
    __builtin_amdgcn_s_setprio(0);

    if (pre) WRT(cur^1);
    __syncthreads();                            // single barrier per iteration
    cur ^= 1;
  } // kt

  // ---- epilogue: fp32 out; lsum for row q=g*4+r from lanes 0..15
  float lso[4];
  #pragma unroll
  for (int r=0; r<4; r++) lso[r] = __shfl(lreg, g*4 + r);
  float* Ob = out + qbase*HD;
  #pragma unroll
  for (int dt=0; dt<8; dt++){
    #pragma unroll
    for (int r=0; r<4; r++){
      Ob[(size_t)(w*16 + g*4 + r)*HD + dt*16 + li] = oacc[dt][r] / lso[r];
    }
  }
  #undef LOADT
  #undef WRT
}

// ---------------- launch -----------------------------------------------------
// d_in = [q, k, v, Wq, bq, Wk, bk, Wv, bv, mask] (confirmed R15).
// ws: (Qh slot unused) | Kimg(32KB x 256) | Vimg | Wbf16 (25.3 MB).
extern "C" void kernel_launch(void* const* d_in, const int* in_sizes, int n_in,
                              void* d_out, int out_size, void* d_ws, size_t ws_size,
                              hipStream_t stream)
{
  short* ws = (short*)d_ws;
  short* wb = ws + 3*PLANE;

  wconv_kernel<<<24, 256, 0, stream>>>(
      (const float*)d_in[3], (const float*)d_in[5], (const float*)d_in[7], wb);

  dim3 pg(BATCH*SEQ/TB, 2);                      // K and V planes only
  proj_kernel<<<pg, 256, 0, stream>>>(
      (const float*)d_in[1], (const float*)d_in[2],
      (const float*)d_in[6], (const float*)d_in[8],
      wb, ws);

  attn_kernel<<<dim3(BATCH*NT3), 256, 0, stream>>>(
      (const float*)d_in[0], (const float*)d_in[4], wb, ws, (float*)d_out);
}